// Round 5
// baseline (186.017 us; speedup 1.0000x reference)
//
#include <hip/hip_runtime.h>

// APMLSparse: B=4, N=M=4096, D=3.
// loss = sum_rows sum_{kept j} p_ij * d_ij, p = softmax_j(-d_i),
// kept = descending-p prefix until cumulative mass >= P_MIN = 0.8.
//
// R12: R10 base (proven 125 us) + three PURE instruction deletions.
// Model (R7-R11): duration tracks total VALU instruction count
// (VALUBusy*dur ~ const 1.31-1.38 for lean variants; 1.54-1.59 for the
// two bloated regressions R8/R11). R11's fused pass ADDED ops (3 ballots
// +3 popc+mbcnt/k vs A0's 2+2 and B's 1+1+mbcnt) + code bloat => revert.
// Deletions vs R10:
//  1. y repacked [m][3] -> float4 [m] once per launch (tiny kernel into
//     d_ws): setup does 1 dwordx4 load/elem instead of 3 dword loads.
//  2. No block barrier: each wave writes partial[row] (rows are
//     wave-private); wacc/__syncthreads deleted; waves retire
//     independently. Deterministic 2nd-stage reduce over 16384 rows.
//  3. pmax/dppMax setup deleted: pTop = 1.0f (p = exp(-d) < 1 strictly;
//     path proven in R8/R9/R11, exonerated from R11's regression).
// A0 dual pass, 4-chain probes, Phase B, C1, C2, Phase D, zl/spd
// ordering: byte-identical to R10.

#define MCOLS 4096
#define KPT   64            // 4096 / 64 lanes
#define WPB   4             // waves per block
#define P_MIN 0.8f

// ---- DPP wave64 reductions (old=0 => disabled/out-of-range lanes add 0) ----
template <int CTRL, int RM, int BM, bool BC>
__device__ __forceinline__ float dpp_mov0(float x) {
    return __int_as_float(__builtin_amdgcn_update_dpp(
        0, __float_as_int(x), CTRL, RM, BM, BC));
}
__device__ __forceinline__ float dppSum(float v) {
    v += dpp_mov0<0x111, 0xF, 0xF, true >(v);   // row_shr:1
    v += dpp_mov0<0x112, 0xF, 0xF, true >(v);   // row_shr:2
    v += dpp_mov0<0x114, 0xF, 0xF, true >(v);   // row_shr:4
    v += dpp_mov0<0x118, 0xF, 0xF, true >(v);   // row_shr:8
    v += dpp_mov0<0x142, 0xA, 0xF, false>(v);   // row_bcast15 -> rows 1,3
    v += dpp_mov0<0x143, 0xC, 0xF, false>(v);   // row_bcast31 -> rows 2,3
    return __int_as_float(__builtin_amdgcn_readlane(__float_as_int(v), 63));
}
__device__ __forceinline__ void dppSum2(float& a, float& b) {
    a += dpp_mov0<0x111, 0xF, 0xF, true >(a); b += dpp_mov0<0x111, 0xF, 0xF, true >(b);
    a += dpp_mov0<0x112, 0xF, 0xF, true >(a); b += dpp_mov0<0x112, 0xF, 0xF, true >(b);
    a += dpp_mov0<0x114, 0xF, 0xF, true >(a); b += dpp_mov0<0x114, 0xF, 0xF, true >(b);
    a += dpp_mov0<0x118, 0xF, 0xF, true >(a); b += dpp_mov0<0x118, 0xF, 0xF, true >(b);
    a += dpp_mov0<0x142, 0xA, 0xF, false>(a); b += dpp_mov0<0x142, 0xA, 0xF, false>(b);
    a += dpp_mov0<0x143, 0xC, 0xF, false>(a); b += dpp_mov0<0x143, 0xC, 0xF, false>(b);
    a = __int_as_float(__builtin_amdgcn_readlane(__float_as_int(a), 63));
    b = __int_as_float(__builtin_amdgcn_readlane(__float_as_int(b), 63));
}
__device__ __forceinline__ float dppMax(float v) {   // nonneg inputs only
    v = fmaxf(v, dpp_mov0<0x111, 0xF, 0xF, true >(v));
    v = fmaxf(v, dpp_mov0<0x112, 0xF, 0xF, true >(v));
    v = fmaxf(v, dpp_mov0<0x114, 0xF, 0xF, true >(v));
    v = fmaxf(v, dpp_mov0<0x118, 0xF, 0xF, true >(v));
    v = fmaxf(v, dpp_mov0<0x142, 0xA, 0xF, false>(v));
    v = fmaxf(v, dpp_mov0<0x143, 0xC, 0xF, false>(v));
    return __int_as_float(__builtin_amdgcn_readlane(__float_as_int(v), 63));
}

// One-time y repack: [np][3] floats -> [np] float4 (w = 0).
__global__ __launch_bounds__(256) void apml_repack(
        const float* __restrict__ y, float4* __restrict__ y4, int np) {
    const int i = blockIdx.x * 256 + threadIdx.x;
    if (i < np) {
        y4[i] = make_float4(y[i * 3 + 0], y[i * 3 + 1], y[i * 3 + 2], 0.0f);
    }
}

__global__ __launch_bounds__(WPB * 64) void apml_row_wave(
        const float* __restrict__ x, const float* __restrict__ y,
        const float4* __restrict__ y4,
        float* __restrict__ partial, float* __restrict__ out) {
    __shared__ __align__(16) float scomp[WPB * 256];

    const int tid  = threadIdx.x;
    const int wid  = tid >> 6;
    const int lane = tid & 63;
    const int row  = blockIdx.x * WPB + wid;
    const int b    = row >> 12;                 // row / 4096

    const float x0 = x[row * 3 + 0];
    const float x1 = x[row * 3 + 1];
    const float x2 = x[row * 3 + 2];

    // ---- setup: p = exp(-d), register-resident; Z via DPP ----
    // zl chain order is value-critical (Z) -> serial, unchanged.
    float p[KPT];
    float zl = 0.0f;
    if (y4) {
        const float4* y4b = y4 + (size_t)b * MCOLS;
        #pragma unroll
        for (int k = 0; k < KPT; ++k) {
            const float4 v = y4b[k * 64 + lane];
            const float dx = x0 - v.x, dy = x1 - v.y, dz = x2 - v.z;
            const float sq = fmaxf(dx * dx + dy * dy + dz * dz, 1e-12f);
            const float pk = __expf(-sqrtf(sq));
            p[k] = pk;
            zl  += pk;
        }
    } else {
        const float* yb = y + (size_t)b * MCOLS * 3;
        #pragma unroll
        for (int k = 0; k < KPT; ++k) {
            const int j = k * 64 + lane;
            const float y0 = yb[j * 3 + 0];
            const float y1 = yb[j * 3 + 1];
            const float y2 = yb[j * 3 + 2];
            const float dx = x0 - y0, dy = x1 - y1, dz = x2 - y2;
            const float sq = fmaxf(dx * dx + dy * dy + dz * dz, 1e-12f);
            const float pk = __expf(-sqrtf(sq));
            p[k] = pk;
            zl  += pk;
        }
    }
    const float Z      = dppSum(zl);
    const float target = P_MIN * Z;
    const float pTop   = 1.0f;   // p = exp(-d), d >= 1e-6 => p < 1 strictly

    // ---- sampled warm-start: 5 probes on p[0..3] (first 256 elements) ----
    float ssl = 0.0f, ssh = pTop;
    {
        float eGl = 16.0f * dppSum(p[0] + p[1] + p[2] + p[3]);  // Ghat(0)
        float eGh = 0.0f;
        for (int it = 0; it < 5; ++it) {
            float s;
            if (it & 1) {
                s = 0.5f * (ssl + ssh);
            } else {
                const float den = fmaxf(eGl - eGh, 1e-30f);
                s = ssl + (ssh - ssl) * ((eGl - target) / den);
            }
            if (!(s > ssl && s < ssh)) s = 0.5f * (ssl + ssh);
            if (!(s > ssl && s < ssh)) break;
            float m = 0.0f;
            #pragma unroll
            for (int q = 0; q < 4; ++q) m += (p[q] >= s) ? p[q] : 0.0f;
            m = 16.0f * dppSum(m);
            if (m >= target) { ssl = s; eGl = m; }
            else             { ssh = s; eGh = m; }
        }
    }

    // ---- Phase A0: dual-threshold pass, evaluates ssl AND ssh at once ----
    // Invariant from here: G(sl) >= target > G(sh), G(s) = mass of {p >= s}.
    float sl = 0.0f, sh = pTop;
    float Gl = Z,    Gh = 0.0f;
    int   Cl = MCOLS, Ch = 0;
    {
        float ml = 0.0f, mh = 0.0f;
        int   cl_ = 0,   ch_ = 0;
        #pragma unroll
        for (int k = 0; k < KPT; ++k) {
            const float pk = p[k];
            const bool gl = (pk >= ssl);
            const bool gh = (pk >= ssh);
            ml += gl ? pk : 0.0f; cl_ += (int)__popcll(__ballot(gl));
            mh += gh ? pk : 0.0f; ch_ += (int)__popcll(__ballot(gh));
        }
        dppSum2(ml, mh);
        if (ml >= target) { sl = ssl; Gl = ml; Cl = cl_; }
        else              { sh = ssl; Gh = ml; Ch = cl_; }
        if (mh >= target) { sl = ssh; Gl = mh; Cl = ch_; }
        else if (ssh < sh){ sh = ssh; Gh = mh; Ch = ch_; }
    }

    // ---- Phase A: exact probes until band <= 256 (4-chain scans) ----
    for (int it = 0; it < 10 && (Cl - Ch) > 256; ++it) {
        float s;
        if (it & 1) {
            s = 0.5f * (sl + sh);
        } else {
            const float den = fmaxf(Gl - Gh, 1e-30f);
            s = sl + (sh - sl) * ((Gl - target) / den);
        }
        if (!(s > sl && s < sh)) s = 0.5f * (sl + sh);
        if (!(s > sl && s < sh)) break;        // ulp-width bracket

        float m0 = 0.0f, m1 = 0.0f, m2 = 0.0f, m3 = 0.0f;
        int   c = 0;
        #pragma unroll
        for (int k = 0; k < KPT; k += 4) {
            const bool g0 = (p[k]     >= s);
            const bool g1 = (p[k + 1] >= s);
            const bool g2 = (p[k + 2] >= s);
            const bool g3 = (p[k + 3] >= s);
            m0 += g0 ? p[k]     : 0.0f; c += (int)__popcll(__ballot(g0));
            m1 += g1 ? p[k + 1] : 0.0f; c += (int)__popcll(__ballot(g1));
            m2 += g2 ? p[k + 2] : 0.0f; c += (int)__popcll(__ballot(g2));
            m3 += g3 ? p[k + 3] : 0.0f; c += (int)__popcll(__ballot(g3));
        }
        const float m = dppSum((m0 + m1) + (m2 + m3));
        if (m >= target) { sl = s; Gl = m; Cl = c; }
        else             { sh = s; Gh = m; Ch = c; }
    }

    // ---- Phase B: compact band [sl, sh) into 4 regs per lane ----
    int C = 0;
    #pragma unroll
    for (int k = 0; k < KPT; ++k) {
        const bool band = (p[k] >= sl) && (p[k] < sh);
        const unsigned long long mk = __ballot(band);
        if (band) {
            const unsigned mlo = (unsigned)mk, mhi = (unsigned)(mk >> 32);
            const int within = __builtin_amdgcn_mbcnt_hi(
                                   mhi, __builtin_amdgcn_mbcnt_lo(mlo, 0));
            const int pos = C + within;
            if (pos < 256) scomp[wid * 256 + pos] = p[k];
        }
        C += (int)__popcll(mk);
    }
    __builtin_amdgcn_s_waitcnt(0);             // drain ds_writes (same wave)
    float cp[4];
    bool  cv[4];
    #pragma unroll
    for (int q = 0; q < 4; ++q) {
        const int idx = q * 64 + lane;
        cv[q] = (idx < C) && (idx < 256);
        cp[q] = cv[q] ? scomp[wid * 256 + idx] : 0.0f;
    }

    float pstar, mb = 0.0f;
    int   cnt = 1;
    bool  haveTie;

    if (C > 256) {
        // fallback (rare): keep everything >= sl (off by <=2 boundary elems)
        pstar = (sl > 0.0f) ? __uint_as_float(__float_as_uint(sl) - 1u) : 0.0f;
        haveTie = false;
    } else {
        // ---- Phase C1: cheap fine probes on the compact set ----
        float lo_s = sl, hi_s = sh, lo_G = Gl, hi_G = Gh;
        int   lo_C = Cl, hi_C = Ch;
        for (int it = 0; it < 10 && (lo_C - hi_C) > 2; ++it) {
            float s;
            if (it & 1) {
                s = 0.5f * (lo_s + hi_s);
            } else {
                const float den = fmaxf(lo_G - hi_G, 1e-30f);
                s = lo_s + (hi_s - lo_s) * ((lo_G - target) / den);
            }
            if (!(s > lo_s && s < hi_s)) s = 0.5f * (lo_s + hi_s);
            if (!(s > lo_s && s < hi_s)) break;

            float m = 0.0f;
            int   c = Ch;
            #pragma unroll
            for (int q = 0; q < 4; ++q) {
                const bool ge = cv[q] && (cp[q] >= s);
                m += ge ? cp[q] : 0.0f;
                c += (int)__popcll(__ballot(ge));
            }
            m = Gh + dppSum(m);
            if (m >= target) { lo_s = s; lo_G = m; lo_C = c; }
            else             { hi_s = s; hi_G = m; hi_C = c; }
        }

        // ---- Phase C2: exact distinct-value walk downward from hi_s ----
        float scur = hi_s, M = hi_G;
        bool ok = false;
        pstar = lo_s;
        for (int e = 0; e < 16; ++e) {
            float vl = 0.0f;
            #pragma unroll
            for (int q = 0; q < 4; ++q)
                vl = fmaxf(vl, (cv[q] && cp[q] < scur) ? cp[q] : 0.0f);
            const float v = dppMax(vl);
            if (!(v > 0.0f)) break;            // fp knife-edge; fallback
            int cvn = 0;
            #pragma unroll
            for (int q = 0; q < 4; ++q)
                cvn += (int)__popcll(__ballot(cv[q] && (cp[q] == v)));
            const float Mn = M + v * (float)cvn;  // exact: ties bit-identical
            if (Mn >= target) { pstar = v; mb = M; cnt = cvn; ok = true; break; }
            M = Mn; scur = v;
        }
        haveTie = ok;
        if (!ok) {
            pstar = (lo_s > 0.0f) ? __uint_as_float(__float_as_uint(lo_s) - 1u)
                                  : 0.0f;
        }
    }

    // ---- Phase D: spd = sum_{p > p*} p * (-log p) via select-to-1 ----
    // (order value-critical: unchanged)
    float spd = 0.0f;
    #pragma unroll
    for (int k = 0; k < KPT; ++k) {
        const float t = (p[k] > pstar) ? p[k] : 1.0f;   // log(1) = 0
        spd += t * (-__logf(t));
    }
    spd = dppSum(spd);

    if (lane == 0) {
        float tie = 0.0f;
        if (haveTie) {
            const float R = (target - mb) / pstar;      // exclusive-csum rule
            int q = (int)ceilf(R);
            if (q < 1) q = 1;
            if (q > cnt) q = cnt;
            tie = (float)q * pstar * (-__logf(pstar));
        }
        const float v = (spd + tie) / Z;
        if (partial) partial[row] = v;       // per-wave, no barrier, no atomic
        else         atomicAdd(out, v);      // ws_size fallback
    }
}

// Deterministic 2nd-stage reduce: n (<=16384) floats -> out[0].
__global__ __launch_bounds__(1024) void apml_reduce(
        const float* __restrict__ partial, float* __restrict__ out, int n) {
    __shared__ float s[16];
    const int t = threadIdx.x;
    float a = 0.0f;
    #pragma unroll
    for (int q = 0; q < 16; ++q) {
        const int i = t * 16 + q;
        a += (i < n) ? partial[i] : 0.0f;
    }
    a = dppSum(a);
    if ((t & 63) == 0) s[t >> 6] = a;
    __syncthreads();
    if (t == 0) {
        float r = 0.0f;
        #pragma unroll
        for (int w = 0; w < 16; ++w) r += s[w];
        out[0] = r;
    }
}

extern "C" void kernel_launch(void* const* d_in, const int* in_sizes, int n_in,
                              void* d_out, int out_size, void* d_ws, size_t ws_size,
                              hipStream_t stream) {
    const float* x = (const float*)d_in[0];   // [B, N, 3]
    const float* y = (const float*)d_in[1];   // [B, M, 3]
    float* out = (float*)d_out;               // scalar

    const int nrows = in_sizes[0] / 3;        // B * N = 16384
    const int np    = in_sizes[1] / 3;        // B * M = 16384 y-points
    const int nblocks = nrows / WPB;          // 4096

    const size_t y4_bytes   = (size_t)np * sizeof(float4);
    const size_t part_bytes = (size_t)nrows * sizeof(float);

    if (d_ws && ws_size >= y4_bytes + part_bytes && nrows <= 16384) {
        float4* y4     = (float4*)d_ws;
        float* partial = (float*)((char*)d_ws + y4_bytes);
        apml_repack<<<(np + 255) / 256, 256, 0, stream>>>(y, y4, np);
        apml_row_wave<<<nblocks, WPB * 64, 0, stream>>>(x, y, y4, partial, out);
        apml_reduce<<<1, 1024, 0, stream>>>(partial, out, nrows);
    } else if (d_ws && ws_size >= part_bytes && nrows <= 16384) {
        float* partial = (float*)d_ws;
        apml_row_wave<<<nblocks, WPB * 64, 0, stream>>>(x, y, nullptr, partial, out);
        apml_reduce<<<1, 1024, 0, stream>>>(partial, out, nrows);
    } else {
        hipMemsetAsync(out, 0, sizeof(float), stream);   // capture-legal
        apml_row_wave<<<nblocks, WPB * 64, 0, stream>>>(x, y, nullptr, nullptr, out);
    }
}

// Round 6
// 183.861 us; speedup vs baseline: 1.0117x; 1.0117x over previous
//
#include <hip/hip_runtime.h>

// APMLSparse: B=4, N=M=4096, D=3.
// loss = sum_rows sum_{kept j} p_ij * d_ij, p = softmax_j(-d_i),
// kept = descending-p prefix until cumulative mass >= P_MIN = 0.8.
//
// R13: residency experiment. Model after R7-R12: total issue ~5000 cyc/wave
// (stable), real VALU util pinned ~27%, dur = issue/util. Occupancy ~15
// waves/CU ~= 3.75 blocks/CU at WPB=4 => residency may be BLOCK-count
// limited, not wave-limited (confounded until now). One variable: WPB 4->8
// (512-thread blocks, 2048 blocks). If block-limited: 4 blocks x 8 waves =
// 32 waves/CU => util ~2x => dur ~75-95 us. If wave-limited: neutral, and
// R14 pivots to code-size/I$ (rolled loops + LDS-resident p).
// R12 post-mortem folded in: repack REVERTED (compiler already merges the
// 3 scalar y loads into global_load_dwordx3; float4 deleted nothing and
// the cross-XCD L2-incoherent y4 re-fetch added +265KB HBM traffic).
// Kept from R12 (mechanically safe): no block barrier -- each wave writes
// partial[row]; deterministic 2-stage reduce; pTop = 1.0f.
// All phase code byte-identical to R10.

#define MCOLS 4096
#define KPT   64            // 4096 / 64 lanes
#define WPB   8             // waves per block  (R13: the one variable)
#define P_MIN 0.8f

// ---- DPP wave64 reductions (old=0 => disabled/out-of-range lanes add 0) ----
template <int CTRL, int RM, int BM, bool BC>
__device__ __forceinline__ float dpp_mov0(float x) {
    return __int_as_float(__builtin_amdgcn_update_dpp(
        0, __float_as_int(x), CTRL, RM, BM, BC));
}
__device__ __forceinline__ float dppSum(float v) {
    v += dpp_mov0<0x111, 0xF, 0xF, true >(v);   // row_shr:1
    v += dpp_mov0<0x112, 0xF, 0xF, true >(v);   // row_shr:2
    v += dpp_mov0<0x114, 0xF, 0xF, true >(v);   // row_shr:4
    v += dpp_mov0<0x118, 0xF, 0xF, true >(v);   // row_shr:8
    v += dpp_mov0<0x142, 0xA, 0xF, false>(v);   // row_bcast15 -> rows 1,3
    v += dpp_mov0<0x143, 0xC, 0xF, false>(v);   // row_bcast31 -> rows 2,3
    return __int_as_float(__builtin_amdgcn_readlane(__float_as_int(v), 63));
}
__device__ __forceinline__ void dppSum2(float& a, float& b) {
    a += dpp_mov0<0x111, 0xF, 0xF, true >(a); b += dpp_mov0<0x111, 0xF, 0xF, true >(b);
    a += dpp_mov0<0x112, 0xF, 0xF, true >(a); b += dpp_mov0<0x112, 0xF, 0xF, true >(b);
    a += dpp_mov0<0x114, 0xF, 0xF, true >(a); b += dpp_mov0<0x114, 0xF, 0xF, true >(b);
    a += dpp_mov0<0x118, 0xF, 0xF, true >(a); b += dpp_mov0<0x118, 0xF, 0xF, true >(b);
    a += dpp_mov0<0x142, 0xA, 0xF, false>(a); b += dpp_mov0<0x142, 0xA, 0xF, false>(b);
    a += dpp_mov0<0x143, 0xC, 0xF, false>(a); b += dpp_mov0<0x143, 0xC, 0xF, false>(b);
    a = __int_as_float(__builtin_amdgcn_readlane(__float_as_int(a), 63));
    b = __int_as_float(__builtin_amdgcn_readlane(__float_as_int(b), 63));
}
__device__ __forceinline__ float dppMax(float v) {   // nonneg inputs only
    v = fmaxf(v, dpp_mov0<0x111, 0xF, 0xF, true >(v));
    v = fmaxf(v, dpp_mov0<0x112, 0xF, 0xF, true >(v));
    v = fmaxf(v, dpp_mov0<0x114, 0xF, 0xF, true >(v));
    v = fmaxf(v, dpp_mov0<0x118, 0xF, 0xF, true >(v));
    v = fmaxf(v, dpp_mov0<0x142, 0xA, 0xF, false>(v));
    v = fmaxf(v, dpp_mov0<0x143, 0xC, 0xF, false>(v));
    return __int_as_float(__builtin_amdgcn_readlane(__float_as_int(v), 63));
}

__global__ __launch_bounds__(WPB * 64) void apml_row_wave(
        const float* __restrict__ x, const float* __restrict__ y,
        float* __restrict__ partial, float* __restrict__ out) {
    __shared__ __align__(16) float scomp[WPB * 256];

    const int tid  = threadIdx.x;
    const int wid  = tid >> 6;
    const int lane = tid & 63;
    const int row  = blockIdx.x * WPB + wid;
    const int b    = row >> 12;                 // row / 4096

    const float x0 = x[row * 3 + 0];
    const float x1 = x[row * 3 + 1];
    const float x2 = x[row * 3 + 2];
    const float* yb = y + (size_t)b * MCOLS * 3;

    // ---- setup: p = exp(-d), register-resident; Z via DPP ----
    float p[KPT];
    float zl = 0.0f;
    #pragma unroll
    for (int k = 0; k < KPT; ++k) {
        const int j = k * 64 + lane;
        const float y0 = yb[j * 3 + 0];
        const float y1 = yb[j * 3 + 1];
        const float y2 = yb[j * 3 + 2];
        const float dx = x0 - y0, dy = x1 - y1, dz = x2 - y2;
        const float sq = fmaxf(dx * dx + dy * dy + dz * dz, 1e-12f); // EPS^2
        const float pk = __expf(-sqrtf(sq));
        p[k] = pk;
        zl  += pk;
    }
    const float Z      = dppSum(zl);
    const float target = P_MIN * Z;
    const float pTop   = 1.0f;   // p = exp(-d), d >= 1e-6 => p < 1 strictly

    // ---- sampled warm-start: 5 probes on p[0..3] (first 256 elements) ----
    float ssl = 0.0f, ssh = pTop;
    {
        float eGl = 16.0f * dppSum(p[0] + p[1] + p[2] + p[3]);  // Ghat(0)
        float eGh = 0.0f;
        for (int it = 0; it < 5; ++it) {
            float s;
            if (it & 1) {
                s = 0.5f * (ssl + ssh);
            } else {
                const float den = fmaxf(eGl - eGh, 1e-30f);
                s = ssl + (ssh - ssl) * ((eGl - target) / den);
            }
            if (!(s > ssl && s < ssh)) s = 0.5f * (ssl + ssh);
            if (!(s > ssl && s < ssh)) break;
            float m = 0.0f;
            #pragma unroll
            for (int q = 0; q < 4; ++q) m += (p[q] >= s) ? p[q] : 0.0f;
            m = 16.0f * dppSum(m);
            if (m >= target) { ssl = s; eGl = m; }
            else             { ssh = s; eGh = m; }
        }
    }

    // ---- Phase A0: dual-threshold pass, evaluates ssl AND ssh at once ----
    // Invariant from here: G(sl) >= target > G(sh), G(s) = mass of {p >= s}.
    float sl = 0.0f, sh = pTop;
    float Gl = Z,    Gh = 0.0f;
    int   Cl = MCOLS, Ch = 0;
    {
        float ml = 0.0f, mh = 0.0f;
        int   cl_ = 0,   ch_ = 0;
        #pragma unroll
        for (int k = 0; k < KPT; ++k) {
            const float pk = p[k];
            const bool gl = (pk >= ssl);
            const bool gh = (pk >= ssh);
            ml += gl ? pk : 0.0f; cl_ += (int)__popcll(__ballot(gl));
            mh += gh ? pk : 0.0f; ch_ += (int)__popcll(__ballot(gh));
        }
        dppSum2(ml, mh);
        if (ml >= target) { sl = ssl; Gl = ml; Cl = cl_; }
        else              { sh = ssl; Gh = ml; Ch = cl_; }
        if (mh >= target) { sl = ssh; Gl = mh; Cl = ch_; }
        else if (ssh < sh){ sh = ssh; Gh = mh; Ch = ch_; }
    }

    // ---- Phase A: exact probes until band <= 256 (4-chain scans) ----
    for (int it = 0; it < 10 && (Cl - Ch) > 256; ++it) {
        float s;
        if (it & 1) {
            s = 0.5f * (sl + sh);
        } else {
            const float den = fmaxf(Gl - Gh, 1e-30f);
            s = sl + (sh - sl) * ((Gl - target) / den);
        }
        if (!(s > sl && s < sh)) s = 0.5f * (sl + sh);
        if (!(s > sl && s < sh)) break;        // ulp-width bracket

        float m0 = 0.0f, m1 = 0.0f, m2 = 0.0f, m3 = 0.0f;
        int   c = 0;
        #pragma unroll
        for (int k = 0; k < KPT; k += 4) {
            const bool g0 = (p[k]     >= s);
            const bool g1 = (p[k + 1] >= s);
            const bool g2 = (p[k + 2] >= s);
            const bool g3 = (p[k + 3] >= s);
            m0 += g0 ? p[k]     : 0.0f; c += (int)__popcll(__ballot(g0));
            m1 += g1 ? p[k + 1] : 0.0f; c += (int)__popcll(__ballot(g1));
            m2 += g2 ? p[k + 2] : 0.0f; c += (int)__popcll(__ballot(g2));
            m3 += g3 ? p[k + 3] : 0.0f; c += (int)__popcll(__ballot(g3));
        }
        const float m = dppSum((m0 + m1) + (m2 + m3));
        if (m >= target) { sl = s; Gl = m; Cl = c; }
        else             { sh = s; Gh = m; Ch = c; }
    }

    // ---- Phase B: compact band [sl, sh) into 4 regs per lane ----
    int C = 0;
    #pragma unroll
    for (int k = 0; k < KPT; ++k) {
        const bool band = (p[k] >= sl) && (p[k] < sh);
        const unsigned long long mk = __ballot(band);
        if (band) {
            const unsigned mlo = (unsigned)mk, mhi = (unsigned)(mk >> 32);
            const int within = __builtin_amdgcn_mbcnt_hi(
                                   mhi, __builtin_amdgcn_mbcnt_lo(mlo, 0));
            const int pos = C + within;
            if (pos < 256) scomp[wid * 256 + pos] = p[k];
        }
        C += (int)__popcll(mk);
    }
    __builtin_amdgcn_s_waitcnt(0);             // drain ds_writes (same wave)
    float cp[4];
    bool  cv[4];
    #pragma unroll
    for (int q = 0; q < 4; ++q) {
        const int idx = q * 64 + lane;
        cv[q] = (idx < C) && (idx < 256);
        cp[q] = cv[q] ? scomp[wid * 256 + idx] : 0.0f;
    }

    float pstar, mb = 0.0f;
    int   cnt = 1;
    bool  haveTie;

    if (C > 256) {
        // fallback (rare): keep everything >= sl (off by <=2 boundary elems)
        pstar = (sl > 0.0f) ? __uint_as_float(__float_as_uint(sl) - 1u) : 0.0f;
        haveTie = false;
    } else {
        // ---- Phase C1: cheap fine probes on the compact set ----
        float lo_s = sl, hi_s = sh, lo_G = Gl, hi_G = Gh;
        int   lo_C = Cl, hi_C = Ch;
        for (int it = 0; it < 10 && (lo_C - hi_C) > 2; ++it) {
            float s;
            if (it & 1) {
                s = 0.5f * (lo_s + hi_s);
            } else {
                const float den = fmaxf(lo_G - hi_G, 1e-30f);
                s = lo_s + (hi_s - lo_s) * ((lo_G - target) / den);
            }
            if (!(s > lo_s && s < hi_s)) s = 0.5f * (lo_s + hi_s);
            if (!(s > lo_s && s < hi_s)) break;

            float m = 0.0f;
            int   c = Ch;
            #pragma unroll
            for (int q = 0; q < 4; ++q) {
                const bool ge = cv[q] && (cp[q] >= s);
                m += ge ? cp[q] : 0.0f;
                c += (int)__popcll(__ballot(ge));
            }
            m = Gh + dppSum(m);
            if (m >= target) { lo_s = s; lo_G = m; lo_C = c; }
            else             { hi_s = s; hi_G = m; hi_C = c; }
        }

        // ---- Phase C2: exact distinct-value walk downward from hi_s ----
        float scur = hi_s, M = hi_G;
        bool ok = false;
        pstar = lo_s;
        for (int e = 0; e < 16; ++e) {
            float vl = 0.0f;
            #pragma unroll
            for (int q = 0; q < 4; ++q)
                vl = fmaxf(vl, (cv[q] && cp[q] < scur) ? cp[q] : 0.0f);
            const float v = dppMax(vl);
            if (!(v > 0.0f)) break;            // fp knife-edge; fallback
            int cvn = 0;
            #pragma unroll
            for (int q = 0; q < 4; ++q)
                cvn += (int)__popcll(__ballot(cv[q] && (cp[q] == v)));
            const float Mn = M + v * (float)cvn;  // exact: ties bit-identical
            if (Mn >= target) { pstar = v; mb = M; cnt = cvn; ok = true; break; }
            M = Mn; scur = v;
        }
        haveTie = ok;
        if (!ok) {
            pstar = (lo_s > 0.0f) ? __uint_as_float(__float_as_uint(lo_s) - 1u)
                                  : 0.0f;
        }
    }

    // ---- Phase D: spd = sum_{p > p*} p * (-log p) via select-to-1 ----
    float spd = 0.0f;
    #pragma unroll
    for (int k = 0; k < KPT; ++k) {
        const float t = (p[k] > pstar) ? p[k] : 1.0f;   // log(1) = 0
        spd += t * (-__logf(t));
    }
    spd = dppSum(spd);

    if (lane == 0) {
        float tie = 0.0f;
        if (haveTie) {
            const float R = (target - mb) / pstar;      // exclusive-csum rule
            int q = (int)ceilf(R);
            if (q < 1) q = 1;
            if (q > cnt) q = cnt;
            tie = (float)q * pstar * (-__logf(pstar));
        }
        const float v = (spd + tie) / Z;
        if (partial) partial[row] = v;       // per-wave, no barrier, no atomic
        else         atomicAdd(out, v);      // ws_size fallback
    }
}

// Deterministic 2nd-stage reduce: n (<=16384) floats -> out[0].
__global__ __launch_bounds__(1024) void apml_reduce(
        const float* __restrict__ partial, float* __restrict__ out, int n) {
    __shared__ float s[16];
    const int t = threadIdx.x;
    float a = 0.0f;
    #pragma unroll
    for (int q = 0; q < 16; ++q) {
        const int i = t * 16 + q;
        a += (i < n) ? partial[i] : 0.0f;
    }
    a = dppSum(a);
    if ((t & 63) == 0) s[t >> 6] = a;
    __syncthreads();
    if (t == 0) {
        float r = 0.0f;
        #pragma unroll
        for (int w = 0; w < 16; ++w) r += s[w];
        out[0] = r;
    }
}

extern "C" void kernel_launch(void* const* d_in, const int* in_sizes, int n_in,
                              void* d_out, int out_size, void* d_ws, size_t ws_size,
                              hipStream_t stream) {
    const float* x = (const float*)d_in[0];   // [B, N, 3]
    const float* y = (const float*)d_in[1];   // [B, M, 3]
    float* out = (float*)d_out;               // scalar

    const int nrows = in_sizes[0] / 3;        // B * N = 16384
    const int nblocks = nrows / WPB;          // 2048

    const size_t part_bytes = (size_t)nrows * sizeof(float);

    if (d_ws && ws_size >= part_bytes && nrows <= 16384) {
        float* partial = (float*)d_ws;
        apml_row_wave<<<nblocks, WPB * 64, 0, stream>>>(x, y, partial, out);
        apml_reduce<<<1, 1024, 0, stream>>>(partial, out, nrows);
    } else {
        hipMemsetAsync(out, 0, sizeof(float), stream);   // capture-legal
        apml_row_wave<<<nblocks, WPB * 64, 0, stream>>>(x, y, nullptr, out);
    }
}

// Round 7
// 166.285 us; speedup vs baseline: 1.1187x; 1.1057x over previous
//
#include <hip/hip_runtime.h>

// APMLSparse: B=4, N=M=4096, D=3.
// loss = sum_rows sum_{kept j} p_ij * d_ij, p = softmax_j(-d_i),
// kept = descending-p prefix until cumulative mass >= P_MIN = 0.8.
//
// R14: R10 base (best: 125 us) + sequential-LATENCY trims only.
// Model update (R12/R13): duration = issue + serial-round latency. Both
// pTop=1.0 variants ran FEWER instructions yet slower (product 1.33 vs
// 1.38) -- dropping pmax costs 1-2 extra probe ROUNDS (each ~600+ cyc of
// DPP+readlane+branch span, only ~400 instr). Every pmax-less version
// (R8/R9/R12/R13) regressed; both good ones (R7/R10) kept it. So: keep
// pmax, and spend instructions only where they delete whole rounds.
// Changes vs R10 (everything else verbatim, incl. barrier+wacc+
// partial[blockIdx]+deterministic reduce, WPB=4):
//  1. Phase D: 4 independent accumulator chains (per-element term
//     bit-identical; add-order reassociation proven tolerated by the
//     R12/R13 final-sum reorder). Serial chain ~256 -> ~70 cyc.
//  2. C1: dual-threshold rounds (interp+bisect per round, dppSum2;
//     correctness-proven in R8/R11). Halves sequential C1 rounds.
//  3. Warm start: dual-probe rounds, 3 rounds ~= 6 probes.

#define MCOLS 4096
#define KPT   64            // 4096 / 64 lanes
#define WPB   4             // waves per block
#define P_MIN 0.8f

// ---- DPP wave64 reductions (old=0 => disabled/out-of-range lanes add 0) ----
template <int CTRL, int RM, int BM, bool BC>
__device__ __forceinline__ float dpp_mov0(float x) {
    return __int_as_float(__builtin_amdgcn_update_dpp(
        0, __float_as_int(x), CTRL, RM, BM, BC));
}
__device__ __forceinline__ float dppSum(float v) {
    v += dpp_mov0<0x111, 0xF, 0xF, true >(v);   // row_shr:1
    v += dpp_mov0<0x112, 0xF, 0xF, true >(v);   // row_shr:2
    v += dpp_mov0<0x114, 0xF, 0xF, true >(v);   // row_shr:4
    v += dpp_mov0<0x118, 0xF, 0xF, true >(v);   // row_shr:8
    v += dpp_mov0<0x142, 0xA, 0xF, false>(v);   // row_bcast15 -> rows 1,3
    v += dpp_mov0<0x143, 0xC, 0xF, false>(v);   // row_bcast31 -> rows 2,3
    return __int_as_float(__builtin_amdgcn_readlane(__float_as_int(v), 63));
}
__device__ __forceinline__ void dppSum2(float& a, float& b) {
    a += dpp_mov0<0x111, 0xF, 0xF, true >(a); b += dpp_mov0<0x111, 0xF, 0xF, true >(b);
    a += dpp_mov0<0x112, 0xF, 0xF, true >(a); b += dpp_mov0<0x112, 0xF, 0xF, true >(b);
    a += dpp_mov0<0x114, 0xF, 0xF, true >(a); b += dpp_mov0<0x114, 0xF, 0xF, true >(b);
    a += dpp_mov0<0x118, 0xF, 0xF, true >(a); b += dpp_mov0<0x118, 0xF, 0xF, true >(b);
    a += dpp_mov0<0x142, 0xA, 0xF, false>(a); b += dpp_mov0<0x142, 0xA, 0xF, false>(b);
    a += dpp_mov0<0x143, 0xC, 0xF, false>(a); b += dpp_mov0<0x143, 0xC, 0xF, false>(b);
    a = __int_as_float(__builtin_amdgcn_readlane(__float_as_int(a), 63));
    b = __int_as_float(__builtin_amdgcn_readlane(__float_as_int(b), 63));
}
__device__ __forceinline__ float dppMax(float v) {   // nonneg inputs only
    v = fmaxf(v, dpp_mov0<0x111, 0xF, 0xF, true >(v));
    v = fmaxf(v, dpp_mov0<0x112, 0xF, 0xF, true >(v));
    v = fmaxf(v, dpp_mov0<0x114, 0xF, 0xF, true >(v));
    v = fmaxf(v, dpp_mov0<0x118, 0xF, 0xF, true >(v));
    v = fmaxf(v, dpp_mov0<0x142, 0xA, 0xF, false>(v));
    v = fmaxf(v, dpp_mov0<0x143, 0xC, 0xF, false>(v));
    return __int_as_float(__builtin_amdgcn_readlane(__float_as_int(v), 63));
}

__global__ __launch_bounds__(WPB * 64) void apml_row_wave(
        const float* __restrict__ x, const float* __restrict__ y,
        float* __restrict__ partial, float* __restrict__ out) {
    __shared__ __align__(16) float scomp[WPB * 256];
    __shared__ float wacc[WPB];

    const int tid  = threadIdx.x;
    const int wid  = tid >> 6;
    const int lane = tid & 63;
    const int row  = blockIdx.x * WPB + wid;
    const int b    = row >> 12;                 // row / 4096

    const float x0 = x[row * 3 + 0];
    const float x1 = x[row * 3 + 1];
    const float x2 = x[row * 3 + 2];
    const float* yb = y + (size_t)b * MCOLS * 3;

    // ---- setup: p = exp(-d), register-resident; Z and pmax via DPP ----
    // zl chain order is value-critical (Z) -> serial, unchanged.
    float p[KPT];
    float zl = 0.0f;
    float pm0 = 0.0f, pm1 = 0.0f, pm2 = 0.0f, pm3 = 0.0f;
    #pragma unroll
    for (int k = 0; k < KPT; ++k) {
        const int j = k * 64 + lane;
        const float y0 = yb[j * 3 + 0];
        const float y1 = yb[j * 3 + 1];
        const float y2 = yb[j * 3 + 2];
        const float dx = x0 - y0, dy = x1 - y1, dz = x2 - y2;
        const float sq = fmaxf(dx * dx + dy * dy + dz * dz, 1e-12f); // EPS^2
        const float pk = __expf(-sqrtf(sq));
        p[k] = pk;
        zl  += pk;
        if      ((k & 3) == 0) pm0 = fmaxf(pm0, pk);
        else if ((k & 3) == 1) pm1 = fmaxf(pm1, pk);
        else if ((k & 3) == 2) pm2 = fmaxf(pm2, pk);
        else                   pm3 = fmaxf(pm3, pk);
    }
    const float Z    = dppSum(zl);
    const float pmax = dppMax(fmaxf(fmaxf(pm0, pm1), fmaxf(pm2, pm3)));
    const float target = P_MIN * Z;
    const float pTop = __uint_as_float(__float_as_uint(pmax) + 1u);

    // ---- sampled warm-start: 3 DUAL rounds (~6 probes) on p[0..3] ----
    float ssl = 0.0f, ssh = pTop;
    {
        float eGl = 16.0f * dppSum(p[0] + p[1] + p[2] + p[3]);  // Ghat(0)
        float eGh = 0.0f;
        for (int it = 0; it < 3; ++it) {
            const float sB = 0.5f * (ssl + ssh);
            if (!(sB > ssl && sB < ssh)) break;
            float sA = ssl + (ssh - ssl) *
                       ((eGl - target) / fmaxf(eGl - eGh, 1e-30f));
            if (!(sA > ssl && sA < ssh)) sA = sB;
            const float t0 = fminf(sA, sB), t1 = fmaxf(sA, sB);

            float a0 = 0.0f, a1 = 0.0f;
            #pragma unroll
            for (int q = 0; q < 4; ++q) {
                a0 += (p[q] >= t0) ? p[q] : 0.0f;
                a1 += (p[q] >= t1) ? p[q] : 0.0f;
            }
            dppSum2(a0, a1);
            const float M0 = 16.0f * a0, M1 = 16.0f * a1;   // M0 >= M1
            if      (M1 >= target) { ssl = t1; eGl = M1; }
            else if (M0 >= target) { ssl = t0; eGl = M0;
                                     ssh = t1; eGh = M1; }
            else                   { ssh = t0; eGh = M0; }
        }
    }

    // ---- Phase A0: dual-threshold pass, evaluates ssl AND ssh at once ----
    // Invariant from here: G(sl) >= target > G(sh), G(s) = mass of {p >= s}.
    float sl = 0.0f, sh = pTop;
    float Gl = Z,    Gh = 0.0f;
    int   Cl = MCOLS, Ch = 0;
    {
        float ml = 0.0f, mh = 0.0f;
        int   cl_ = 0,   ch_ = 0;
        #pragma unroll
        for (int k = 0; k < KPT; ++k) {
            const float pk = p[k];
            const bool gl = (pk >= ssl);
            const bool gh = (pk >= ssh);
            ml += gl ? pk : 0.0f; cl_ += (int)__popcll(__ballot(gl));
            mh += gh ? pk : 0.0f; ch_ += (int)__popcll(__ballot(gh));
        }
        dppSum2(ml, mh);
        if (ml >= target) { sl = ssl; Gl = ml; Cl = cl_; }
        else              { sh = ssl; Gh = ml; Ch = cl_; }
        if (mh >= target) { sl = ssh; Gl = mh; Cl = ch_; }
        else if (ssh < sh){ sh = ssh; Gh = mh; Ch = ch_; }
    }

    // ---- Phase A: exact probes until band <= 256 (4-chain scans) ----
    for (int it = 0; it < 10 && (Cl - Ch) > 256; ++it) {
        float s;
        if (it & 1) {
            s = 0.5f * (sl + sh);
        } else {
            const float den = fmaxf(Gl - Gh, 1e-30f);
            s = sl + (sh - sl) * ((Gl - target) / den);
        }
        if (!(s > sl && s < sh)) s = 0.5f * (sl + sh);
        if (!(s > sl && s < sh)) break;        // ulp-width bracket

        float m0 = 0.0f, m1 = 0.0f, m2 = 0.0f, m3 = 0.0f;
        int   c = 0;
        #pragma unroll
        for (int k = 0; k < KPT; k += 4) {
            const bool g0 = (p[k]     >= s);
            const bool g1 = (p[k + 1] >= s);
            const bool g2 = (p[k + 2] >= s);
            const bool g3 = (p[k + 3] >= s);
            m0 += g0 ? p[k]     : 0.0f; c += (int)__popcll(__ballot(g0));
            m1 += g1 ? p[k + 1] : 0.0f; c += (int)__popcll(__ballot(g1));
            m2 += g2 ? p[k + 2] : 0.0f; c += (int)__popcll(__ballot(g2));
            m3 += g3 ? p[k + 3] : 0.0f; c += (int)__popcll(__ballot(g3));
        }
        const float m = dppSum((m0 + m1) + (m2 + m3));
        if (m >= target) { sl = s; Gl = m; Cl = c; }
        else             { sh = s; Gh = m; Ch = c; }
    }

    // ---- Phase B: compact band [sl, sh) into 4 regs per lane ----
    int C = 0;
    #pragma unroll
    for (int k = 0; k < KPT; ++k) {
        const bool band = (p[k] >= sl) && (p[k] < sh);
        const unsigned long long mk = __ballot(band);
        if (band) {
            const unsigned mlo = (unsigned)mk, mhi = (unsigned)(mk >> 32);
            const int within = __builtin_amdgcn_mbcnt_hi(
                                   mhi, __builtin_amdgcn_mbcnt_lo(mlo, 0));
            const int pos = C + within;
            if (pos < 256) scomp[wid * 256 + pos] = p[k];
        }
        C += (int)__popcll(mk);
    }
    __builtin_amdgcn_s_waitcnt(0);             // drain ds_writes (same wave)
    float cp[4];
    bool  cv[4];
    #pragma unroll
    for (int q = 0; q < 4; ++q) {
        const int idx = q * 64 + lane;
        cv[q] = (idx < C) && (idx < 256);
        cp[q] = cv[q] ? scomp[wid * 256 + idx] : 0.0f;
    }

    float pstar, mb = 0.0f;
    int   cnt = 1;
    bool  haveTie;

    if (C > 256) {
        // fallback (rare): keep everything >= sl (off by <=2 boundary elems)
        pstar = (sl > 0.0f) ? __uint_as_float(__float_as_uint(sl) - 1u) : 0.0f;
        haveTie = false;
    } else {
        // ---- Phase C1: fine probes, 2 thresholds per round ----
        float lo_s = sl, hi_s = sh, lo_G = Gl, hi_G = Gh;
        int   lo_C = Cl, hi_C = Ch;
        for (int it = 0; it < 6 && (lo_C - hi_C) > 2; ++it) {
            const float sB = 0.5f * (lo_s + hi_s);
            if (!(sB > lo_s && sB < hi_s)) break;   // ulp-width bracket
            float sA = lo_s + (hi_s - lo_s) *
                       ((lo_G - target) / fmaxf(lo_G - hi_G, 1e-30f));
            if (!(sA > lo_s && sA < hi_s)) sA = sB;
            const float t0 = fminf(sA, sB), t1 = fmaxf(sA, sB);

            float a0 = 0.0f, a1 = 0.0f;
            int   k0 = 0,    k1 = 0;
            #pragma unroll
            for (int q = 0; q < 4; ++q) {
                const bool g0 = cv[q] && (cp[q] >= t0);
                const bool g1 = cv[q] && (cp[q] >= t1);
                a0 += g0 ? cp[q] : 0.0f; k0 += (int)__popcll(__ballot(g0));
                a1 += g1 ? cp[q] : 0.0f; k1 += (int)__popcll(__ballot(g1));
            }
            dppSum2(a0, a1);
            const float M0 = Gh + a0, M1 = Gh + a1;    // M0 >= M1
            const int   D0 = Ch + k0, D1 = Ch + k1;
            if      (M1 >= target) { lo_s = t1; lo_G = M1; lo_C = D1; }
            else if (M0 >= target) { lo_s = t0; lo_G = M0; lo_C = D0;
                                     hi_s = t1; hi_G = M1; hi_C = D1; }
            else                   { hi_s = t0; hi_G = M0; hi_C = D0; }
        }

        // ---- Phase C2: exact distinct-value walk downward from hi_s ----
        float scur = hi_s, M = hi_G;
        bool ok = false;
        pstar = lo_s;
        for (int e = 0; e < 16; ++e) {
            float vl = 0.0f;
            #pragma unroll
            for (int q = 0; q < 4; ++q)
                vl = fmaxf(vl, (cv[q] && cp[q] < scur) ? cp[q] : 0.0f);
            const float v = dppMax(vl);
            if (!(v > 0.0f)) break;            // fp knife-edge; fallback
            int cvn = 0;
            #pragma unroll
            for (int q = 0; q < 4; ++q)
                cvn += (int)__popcll(__ballot(cv[q] && (cp[q] == v)));
            const float Mn = M + v * (float)cvn;  // exact: ties bit-identical
            if (Mn >= target) { pstar = v; mb = M; cnt = cvn; ok = true; break; }
            M = Mn; scur = v;
        }
        haveTie = ok;
        if (!ok) {
            pstar = (lo_s > 0.0f) ? __uint_as_float(__float_as_uint(lo_s) - 1u)
                                  : 0.0f;
        }
    }

    // ---- Phase D: spd = sum_{p > p*} p * (-log p), 4-chain ----
    // Per-element term bit-identical to R10 (select-to-1 trick); only the
    // add association changes (reassociation tolerance proven R12/R13).
    float s0 = 0.0f, s1 = 0.0f, s2 = 0.0f, s3 = 0.0f;
    #pragma unroll
    for (int k = 0; k < KPT; k += 4) {
        const float t0 = (p[k]     > pstar) ? p[k]     : 1.0f;
        const float t1 = (p[k + 1] > pstar) ? p[k + 1] : 1.0f;
        const float t2 = (p[k + 2] > pstar) ? p[k + 2] : 1.0f;
        const float t3 = (p[k + 3] > pstar) ? p[k + 3] : 1.0f;
        s0 += t0 * (-__logf(t0));
        s1 += t1 * (-__logf(t1));
        s2 += t2 * (-__logf(t2));
        s3 += t3 * (-__logf(t3));
    }
    const float spd = dppSum((s0 + s1) + (s2 + s3));

    if (lane == 0) {
        float tie = 0.0f;
        if (haveTie) {
            const float R = (target - mb) / pstar;      // exclusive-csum rule
            int q = (int)ceilf(R);
            if (q < 1) q = 1;
            if (q > cnt) q = cnt;
            tie = (float)q * pstar * (-__logf(pstar));
        }
        wacc[wid] = (spd + tie) / Z;
    }
    __syncthreads();                     // all waves reach exactly once
    if (tid == 0) {
        const float v = wacc[0] + wacc[1] + wacc[2] + wacc[3];
        if (partial) partial[blockIdx.x] = v;   // no same-address atomic
        else         atomicAdd(out, v);         // ws_size fallback
    }
}

// Deterministic 2nd-stage reduce: nblocks (<=4096) floats -> out[0].
__global__ __launch_bounds__(1024) void apml_reduce(
        const float* __restrict__ partial, float* __restrict__ out, int n) {
    __shared__ float s[16];
    const int t = threadIdx.x;
    float a = 0.0f;
    #pragma unroll
    for (int q = 0; q < 4; ++q) {
        const int i = t * 4 + q;
        a += (i < n) ? partial[i] : 0.0f;
    }
    a = dppSum(a);
    if ((t & 63) == 0) s[t >> 6] = a;
    __syncthreads();
    if (t == 0) {
        float r = 0.0f;
        #pragma unroll
        for (int w = 0; w < 16; ++w) r += s[w];
        out[0] = r;
    }
}

extern "C" void kernel_launch(void* const* d_in, const int* in_sizes, int n_in,
                              void* d_out, int out_size, void* d_ws, size_t ws_size,
                              hipStream_t stream) {
    const float* x = (const float*)d_in[0];   // [B, N, 3]
    const float* y = (const float*)d_in[1];   // [B, M, 3]
    float* out = (float*)d_out;               // scalar

    const int nrows = in_sizes[0] / 3;        // B * N
    const int nblocks = nrows / WPB;          // 4096

    if (d_ws && ws_size >= (size_t)nblocks * sizeof(float) && nblocks <= 4096) {
        float* partial = (float*)d_ws;
        apml_row_wave<<<nblocks, WPB * 64, 0, stream>>>(x, y, partial, out);
        apml_reduce<<<1, 1024, 0, stream>>>(partial, out, nblocks);
    } else {
        hipMemsetAsync(out, 0, sizeof(float), stream);   // capture-legal
        apml_row_wave<<<nblocks, WPB * 64, 0, stream>>>(x, y, nullptr, out);
    }
}